// Round 1
// baseline (106.647 us; speedup 1.0000x reference)
//
#include <hip/hip_runtime.h>
#include <math.h>

#define BB 64
#define TT 2048
#define DD 512
#define TCH 16            // t-chunks in PV pass
#define TC (TT / TCH)     // 128 t per chunk

// ---------------------------------------------------------------------------
// Kernel 1: energy[b,t] = dot(key[b,t,:], query[b,:]); masked -> -inf
// 256 threads = 4 waves per block; each wave computes one (b,t) row.
// Lane i loads float4 at i and i+64 -> fully coalesced 2KB row read.
// ---------------------------------------------------------------------------
__global__ __launch_bounds__(256) void energy_kernel(
    const float* __restrict__ q, const float* __restrict__ k,
    const int* __restrict__ mask, float* __restrict__ energy) {
  const int wave = threadIdx.x >> 6;
  const int lane = threadIdx.x & 63;
  const long long row = (long long)blockIdx.x * 4 + wave;  // b*TT + t
  const int b = (int)(row >> 11);

  const float4* kp4 = (const float4*)(k + row * DD);
  const float4* qp4 = (const float4*)(q + (long long)b * DD);

  float4 ka = kp4[lane];
  float4 kb = kp4[lane + 64];
  float4 qa = qp4[lane];
  float4 qb = qp4[lane + 64];

  float s = ka.x * qa.x + ka.y * qa.y + ka.z * qa.z + ka.w * qa.w +
            kb.x * qb.x + kb.y * qb.y + kb.z * qb.z + kb.w * qb.w;

#pragma unroll
  for (int off = 32; off; off >>= 1) s += __shfl_down(s, off, 64);

  if (lane == 0) {
    energy[row] = mask[row] ? -INFINITY : s;
  }
}

// ---------------------------------------------------------------------------
// Kernel 2: row softmax over T for each b. One block (256 thr) per b.
// Writes attention straight into d_out's attention slot.
// ---------------------------------------------------------------------------
__global__ __launch_bounds__(256) void softmax_kernel(
    const float* __restrict__ energy, float* __restrict__ attn) {
  const int b = blockIdx.x;
  const int tid = threadIdx.x;
  const int wave = tid >> 6;
  const int lane = tid & 63;

  float vals[8];
  float m = -INFINITY;
#pragma unroll
  for (int i = 0; i < 8; i++) {
    vals[i] = energy[b * TT + i * 256 + tid];
    m = fmaxf(m, vals[i]);
  }
#pragma unroll
  for (int off = 32; off; off >>= 1) m = fmaxf(m, __shfl_xor(m, off, 64));

  __shared__ float sm[4];
  __shared__ float ss[4];
  if (lane == 0) sm[wave] = m;
  __syncthreads();
  m = fmaxf(fmaxf(sm[0], sm[1]), fmaxf(sm[2], sm[3]));

  float ssum = 0.f;
#pragma unroll
  for (int i = 0; i < 8; i++) {
    vals[i] = __expf(vals[i] - m);  // exp(-inf) = 0 for masked slots
    ssum += vals[i];
  }
#pragma unroll
  for (int off = 32; off; off >>= 1) ssum += __shfl_xor(ssum, off, 64);
  if (lane == 0) ss[wave] = ssum;
  __syncthreads();
  ssum = ss[0] + ss[1] + ss[2] + ss[3];

  const float inv = 1.0f / ssum;
#pragma unroll
  for (int i = 0; i < 8; i++) {
    attn[b * TT + i * 256 + tid] = vals[i] * inv;
  }
}

// ---------------------------------------------------------------------------
// Kernel 3: partial[b,tc,:] = sum_{t in chunk tc} attn[b,t] * value[b,t,:]
// 128 threads; thread d4 owns float4 at d=4*d4 -> fully coalesced V stream.
// ---------------------------------------------------------------------------
__global__ __launch_bounds__(128) void pv_partial(
    const float* __restrict__ attn, const float* __restrict__ v,
    float* __restrict__ partial) {
  const int b = blockIdx.x;
  const int tc = blockIdx.y;
  const int tid = threadIdx.x;

  const float4* vp = (const float4*)(v + ((long long)b * TT + (long long)tc * TC) * DD);
  const float* ap = attn + b * TT + tc * TC;

  float4 acc = {0.f, 0.f, 0.f, 0.f};
#pragma unroll 4
  for (int t = 0; t < TC; t++) {
    const float a = ap[t];
    const float4 vv = vp[t * 128 + tid];
    acc.x += a * vv.x;
    acc.y += a * vv.y;
    acc.z += a * vv.z;
    acc.w += a * vv.w;
  }
  ((float4*)partial)[(b * TCH + tc) * 128 + tid] = acc;
}

// ---------------------------------------------------------------------------
// Kernel 4: context[b,d] = sum_tc partial[b,tc,d]
// ---------------------------------------------------------------------------
__global__ __launch_bounds__(256) void pv_reduce(
    const float* __restrict__ partial, float* __restrict__ ctx) {
  const int i = blockIdx.x * 256 + threadIdx.x;  // over B*D = 32768
  const int b = i >> 9;
  const int d = i & 511;
  float s = 0.f;
#pragma unroll
  for (int tc = 0; tc < TCH; tc++) s += partial[((b * TCH + tc) << 9) + d];
  ctx[i] = s;
}

// ---------------------------------------------------------------------------
extern "C" void kernel_launch(void* const* d_in, const int* in_sizes, int n_in,
                              void* d_out, int out_size, void* d_ws, size_t ws_size,
                              hipStream_t stream) {
  const float* q    = (const float*)d_in[0];  // [B,D]
  const float* k    = (const float*)d_in[1];  // [B,T,D]
  const float* v    = (const float*)d_in[2];  // [B,T,D]
  const int*   mask = (const int*)d_in[3];    // [B,T], 0/1

  float* out  = (float*)d_out;
  float* ctx  = out;            // [B,D]   first output
  float* attn = out + BB * DD;  // [B,T]   second output

  float* energy  = (float*)d_ws;        // B*T floats   = 512 KB
  float* partial = energy + BB * TT;    // B*TCH*D fl   = 2 MB

  energy_kernel<<<BB * TT / 4, 256, 0, stream>>>(q, k, mask, energy);
  softmax_kernel<<<BB, 256, 0, stream>>>(energy, attn);
  pv_partial<<<dim3(BB, TCH), 128, 0, stream>>>(attn, v, partial);
  pv_reduce<<<BB * DD / 256, 256, 0, stream>>>(partial, ctx);
}